// Round 1
// baseline (816.064 us; speedup 1.0000x reference)
//
#include <hip/hip_runtime.h>
#include <cstddef>
#include <cstdint>

#define B_    8
#define CIN_  256
#define COUT_ 256
#define K_    4
#define H_    128
#define W_    128
#define HW_   (H_ * W_)    // 16384
#define P_    (B_ * HW_)   // 131072
#define BN_EPS 1e-5f

__device__ __forceinline__ void fma4(float4& d, float s, const float4& v) {
    d.x = fmaf(s, v.x, d.x);
    d.y = fmaf(s, v.y, d.y);
    d.z = fmaf(s, v.z, d.z);
    d.w = fmaf(s, v.w, d.w);
}

// ---------------------------------------------------------------------------
// K1: flows (K*2) + softmax weights (K) per pixel.
// Reads x once, coalesced along hw. Emits absolute sample coords
// (sx = w + flow_x, sy = h + flow_y) and softmax weights.
// ---------------------------------------------------------------------------
__global__ __launch_bounds__(256) void k_flows(
    const float* __restrict__ x, const float* __restrict__ off_w,
    const float* __restrict__ off_b, const float* __restrict__ wgt_w,
    const float* __restrict__ wgt_b, float* __restrict__ coords,
    float* __restrict__ swts)
{
    __shared__ float coef[12 * 256];   // [j][c], j: 0..7 = off_w(k*2+d), 8..11 = wgt_w
    const int t = threadIdx.x;
    for (int idx = t; idx < 12 * 256; idx += 256)
        coef[idx] = (idx < 8 * 256) ? off_w[idx] : wgt_w[idx - 8 * 256];
    __syncthreads();

    const int p  = blockIdx.x * 256 + t;       // 16384 % 256 == 0: no b straddle
    const int b  = p >> 14;
    const int hw = p & (HW_ - 1);
    const float* xp = x + (size_t)b * (256 * HW_) + hw;

    float acc[12];
#pragma unroll
    for (int j = 0; j < 12; ++j) acc[j] = 0.f;

#pragma unroll 4
    for (int c = 0; c < 256; ++c) {
        const float xv = xp[(size_t)c * HW_];
#pragma unroll
        for (int j = 0; j < 12; ++j)
            acc[j] = fmaf(xv, coef[j * 256 + c], acc[j]);
    }

    const int w = hw & (W_ - 1);
    const int h = hw >> 7;

    float l[4];
#pragma unroll
    for (int k = 0; k < 4; ++k) {
        const float fx = acc[k * 2 + 0] + off_b[k * 2 + 0];
        const float fy = acc[k * 2 + 1] + off_b[k * 2 + 1];
        coords[(size_t)p * 8 + k * 2 + 0] = (float)w + fx;  // unnormalize(normalize(.)) == identity
        coords[(size_t)p * 8 + k * 2 + 1] = (float)h + fy;
        l[k] = acc[8 + k] + wgt_b[k];
    }
    const float m  = fmaxf(fmaxf(l[0], l[1]), fmaxf(l[2], l[3]));
    const float e0 = __expf(l[0] - m), e1 = __expf(l[1] - m);
    const float e2 = __expf(l[2] - m), e3 = __expf(l[3] - m);
    const float inv = 1.f / (e0 + e1 + e2 + e3);
    swts[(size_t)p * 4 + 0] = e0 * inv;
    swts[(size_t)p * 4 + 1] = e1 * inv;
    swts[(size_t)p * 4 + 2] = e2 * inv;
    swts[(size_t)p * 4 + 3] = e3 * inv;
}

// ---------------------------------------------------------------------------
// K2: proj GEMM. C[p][o] = sum_c x[b,c,hw] * conv_w[o,c] + conv_b[o]
// Block tile: 64 px x 256 out, BK=16. Thread: 4 px (i) x 16 out (j*64+u, f4).
// Output pixel-major proj[p*256 + o].
// ---------------------------------------------------------------------------
__global__ __launch_bounds__(256) void k_proj(
    const float* __restrict__ x, const float* __restrict__ wmat,
    const float* __restrict__ bias, float* __restrict__ proj)
{
    __shared__ alignas(16) float As[16][64];
    __shared__ alignas(16) float Bs[16][256];

    const int t  = threadIdx.x;
    const int tx = t & 15, ty = t >> 4;
    const int p0  = blockIdx.x * 64;           // 16384 % 64 == 0: no b straddle
    const int b   = p0 >> 14;
    const int hw0 = p0 & (HW_ - 1);
    const float* xbase = x + (size_t)b * (256 * HW_) + hw0;

    float4 acc[4][4];   // [px i][o-group j], components along o
#pragma unroll
    for (int i = 0; i < 4; ++i)
#pragma unroll
        for (int j = 0; j < 4; ++j) acc[i][j] = make_float4(0.f, 0.f, 0.f, 0.f);

    for (int c0 = 0; c0 < 256; c0 += 16) {
        // A tile: 16c x 64px, coalesced rows of 64 along hw
#pragma unroll
        for (int i = 0; i < 4; ++i) {
            const int e  = i * 256 + t;
            const int c  = e >> 6;
            const int px = e & 63;
            As[c][px] = xbase[(size_t)(c0 + c) * HW_ + px];
        }
        // B tile: row o=t, 16 consecutive c
        const float4 b0 = *(const float4*)&wmat[t * 256 + c0 + 0];
        const float4 b1 = *(const float4*)&wmat[t * 256 + c0 + 4];
        const float4 b2 = *(const float4*)&wmat[t * 256 + c0 + 8];
        const float4 b3 = *(const float4*)&wmat[t * 256 + c0 + 12];
        Bs[0][t] = b0.x;  Bs[1][t] = b0.y;  Bs[2][t] = b0.z;  Bs[3][t] = b0.w;
        Bs[4][t] = b1.x;  Bs[5][t] = b1.y;  Bs[6][t] = b1.z;  Bs[7][t] = b1.w;
        Bs[8][t] = b2.x;  Bs[9][t] = b2.y;  Bs[10][t] = b2.z; Bs[11][t] = b2.w;
        Bs[12][t] = b3.x; Bs[13][t] = b3.y; Bs[14][t] = b3.z; Bs[15][t] = b3.w;
        __syncthreads();

#pragma unroll
        for (int kk = 0; kk < 16; ++kk) {
            const float4 a4 = *(const float4*)&As[kk][ty * 4];
#pragma unroll
            for (int j = 0; j < 4; ++j) {
                const float4 b4 = *(const float4*)&Bs[kk][tx * 4 + j * 64];
                fma4(acc[0][j], a4.x, b4);
                fma4(acc[1][j], a4.y, b4);
                fma4(acc[2][j], a4.z, b4);
                fma4(acc[3][j], a4.w, b4);
            }
        }
        __syncthreads();
    }

#pragma unroll
    for (int j = 0; j < 4; ++j) {
        const float4 bi = *(const float4*)&bias[tx * 4 + j * 64];
#pragma unroll
        for (int i = 0; i < 4; ++i) {
            float4 v = acc[i][j];
            v.x += bi.x; v.y += bi.y; v.z += bi.z; v.w += bi.w;
            *(float4*)&proj[(size_t)(p0 + ty * 4 + i) * 256 + tx * 4 + j * 64] = v;
        }
    }
}

// ---------------------------------------------------------------------------
// K3: bilinear sampling + weighted sum + add proj + BatchNorm (eval).
// One thread per channel o; block handles 4 pixels. Corner gathers are
// contiguous 1KiB rows of proj (pixel-major), coalesced across the block.
// ---------------------------------------------------------------------------
__global__ __launch_bounds__(256) void k_sample(
    const float* __restrict__ proj, const float* __restrict__ coords,
    const float* __restrict__ swts,
    const float* __restrict__ gamma, const float* __restrict__ beta,
    const float* __restrict__ rmean, const float* __restrict__ rvar,
    float* __restrict__ feat)
{
    const int o = threadIdx.x;
    const float mn  = rmean[o];
    const float inv = gamma[o] * rsqrtf(rvar[o] + BN_EPS);
    const float bt  = beta[o];

    const int pbase = blockIdx.x * 4;          // 16384 % 4 == 0: no b straddle
    const int b = pbase >> 14;
    const float* projb = proj + (size_t)b * HW_ * 256;

#pragma unroll
    for (int pp = 0; pp < 4; ++pp) {
        const int p = pbase + pp;
        float acc = proj[(size_t)p * 256 + o];
#pragma unroll
        for (int k = 0; k < 4; ++k) {
            const float sx = coords[(size_t)p * 8 + k * 2 + 0];  // broadcast load
            const float sy = coords[(size_t)p * 8 + k * 2 + 1];
            const float wk = swts[(size_t)p * 4 + k];
            const float x0f = floorf(sx), y0f = floorf(sy);
            const float fx = sx - x0f, fy = sy - y0f;
            const float x1f = x0f + 1.f, y1f = y0f + 1.f;
            const float vx0 = (x0f >= 0.f && x0f <= (float)(W_ - 1)) ? 1.f : 0.f;
            const float vx1 = (x1f >= 0.f && x1f <= (float)(W_ - 1)) ? 1.f : 0.f;
            const float vy0 = (y0f >= 0.f && y0f <= (float)(H_ - 1)) ? 1.f : 0.f;
            const float vy1 = (y1f >= 0.f && y1f <= (float)(H_ - 1)) ? 1.f : 0.f;
            const int x0 = (int)x0f, y0 = (int)y0f;
            const int cx0 = min(max(x0, 0), W_ - 1);
            const int cx1 = min(max(x0 + 1, 0), W_ - 1);
            const int cy0 = min(max(y0, 0), H_ - 1);
            const int cy1 = min(max(y0 + 1, 0), H_ - 1);
            const float w00 = (1.f - fx) * (1.f - fy) * wk * vx0 * vy0;
            const float w10 = fx * (1.f - fy) * wk * vx1 * vy0;
            const float w01 = (1.f - fx) * fy * wk * vx0 * vy1;
            const float w11 = fx * fy * wk * vx1 * vy1;
            acc = fmaf(w00, projb[(size_t)(cy0 * W_ + cx0) * 256 + o], acc);
            acc = fmaf(w10, projb[(size_t)(cy0 * W_ + cx1) * 256 + o], acc);
            acc = fmaf(w01, projb[(size_t)(cy1 * W_ + cx0) * 256 + o], acc);
            acc = fmaf(w11, projb[(size_t)(cy1 * W_ + cx1) * 256 + o], acc);
        }
        feat[(size_t)p * 256 + o] = (acc - mn) * inv + bt;
    }
}

// ---------------------------------------------------------------------------
// K4: out GEMM. out[b,n,hw] = sum_k feat[p][k] * out_w[n,k] + out_b[n]
// Same tiling as K2 but acc components along px so stores are float4 along hw.
// ---------------------------------------------------------------------------
__global__ __launch_bounds__(256) void k_out(
    const float* __restrict__ feat, const float* __restrict__ wmat,
    const float* __restrict__ bias, float* __restrict__ out)
{
    __shared__ alignas(16) float As[16][68];   // +4 pad: 2-way max on transposed writes
    __shared__ alignas(16) float Bs[16][256];

    const int t  = threadIdx.x;
    const int tx = t & 15, ty = t >> 4;
    const int p0  = blockIdx.x * 64;
    const int b   = p0 >> 14;
    const int hw0 = p0 & (HW_ - 1);

    float4 acc[4][4];   // [n-group j][n-sub u], components along px
#pragma unroll
    for (int j = 0; j < 4; ++j)
#pragma unroll
        for (int u = 0; u < 4; ++u) acc[j][u] = make_float4(0.f, 0.f, 0.f, 0.f);

    for (int c0 = 0; c0 < 256; c0 += 16) {
        // A tile: each thread one float4 of feat row (px = t>>2, c = (t&3)*4)
        {
            const int px = t >> 2;
            const int cc = (t & 3) * 4;
            const float4 a = *(const float4*)&feat[(size_t)(p0 + px) * 256 + c0 + cc];
            As[cc + 0][px] = a.x;
            As[cc + 1][px] = a.y;
            As[cc + 2][px] = a.z;
            As[cc + 3][px] = a.w;
        }
        const float4 b0 = *(const float4*)&wmat[t * 256 + c0 + 0];
        const float4 b1 = *(const float4*)&wmat[t * 256 + c0 + 4];
        const float4 b2 = *(const float4*)&wmat[t * 256 + c0 + 8];
        const float4 b3 = *(const float4*)&wmat[t * 256 + c0 + 12];
        Bs[0][t] = b0.x;  Bs[1][t] = b0.y;  Bs[2][t] = b0.z;  Bs[3][t] = b0.w;
        Bs[4][t] = b1.x;  Bs[5][t] = b1.y;  Bs[6][t] = b1.z;  Bs[7][t] = b1.w;
        Bs[8][t] = b2.x;  Bs[9][t] = b2.y;  Bs[10][t] = b2.z; Bs[11][t] = b2.w;
        Bs[12][t] = b3.x; Bs[13][t] = b3.y; Bs[14][t] = b3.z; Bs[15][t] = b3.w;
        __syncthreads();

#pragma unroll
        for (int kk = 0; kk < 16; ++kk) {
            const float4 a4 = *(const float4*)&As[kk][ty * 4];
#pragma unroll
            for (int j = 0; j < 4; ++j) {
                const float4 b4 = *(const float4*)&Bs[kk][tx * 4 + j * 64];
                fma4(acc[j][0], b4.x, a4);
                fma4(acc[j][1], b4.y, a4);
                fma4(acc[j][2], b4.z, a4);
                fma4(acc[j][3], b4.w, a4);
            }
        }
        __syncthreads();
    }

#pragma unroll
    for (int j = 0; j < 4; ++j) {
#pragma unroll
        for (int u = 0; u < 4; ++u) {
            const int n = tx * 4 + j * 64 + u;
            const float bb = bias[n];
            float4 v = acc[j][u];
            v.x += bb; v.y += bb; v.z += bb; v.w += bb;
            *(float4*)&out[(size_t)((b << 8) + n) * HW_ + hw0 + ty * 4] = v;
        }
    }
}

extern "C" void kernel_launch(void* const* d_in, const int* in_sizes, int n_in,
                              void* d_out, int out_size, void* d_ws, size_t ws_size,
                              hipStream_t stream)
{
    const float* x      = (const float*)d_in[0];
    const float* conv_w = (const float*)d_in[1];
    const float* conv_b = (const float*)d_in[2];
    const float* off_w  = (const float*)d_in[3];
    const float* off_b  = (const float*)d_in[4];
    const float* wgt_w  = (const float*)d_in[5];
    const float* wgt_b  = (const float*)d_in[6];
    const float* gamma  = (const float*)d_in[7];
    const float* beta   = (const float*)d_in[8];
    const float* rmean  = (const float*)d_in[9];
    const float* rvar   = (const float*)d_in[10];
    const float* out_w  = (const float*)d_in[11];
    const float* out_b  = (const float*)d_in[12];

    float* proj   = (float*)d_ws;                       // P*256 fp32 = 128 MiB
    float* feat   = proj   + (size_t)P_ * 256;          // P*256 fp32 = 128 MiB
    float* coords = feat   + (size_t)P_ * 256;          // P*8 = 4 MiB
    float* swts   = coords + (size_t)P_ * 8;            // P*4 = 2 MiB

    k_flows <<<P_ / 256, 256, 0, stream>>>(x, off_w, off_b, wgt_w, wgt_b, coords, swts);
    k_proj  <<<P_ / 64,  256, 0, stream>>>(x, conv_w, conv_b, proj);
    k_sample<<<P_ / 4,   256, 0, stream>>>(proj, coords, swts, gamma, beta, rmean, rvar, feat);
    k_out   <<<P_ / 64,  256, 0, stream>>>(feat, out_w, out_b, (float*)d_out);
}

// Round 2
// 456.566 us; speedup vs baseline: 1.7874x; 1.7874x over previous
//
#include <hip/hip_runtime.h>
#include <cstddef>
#include <cstdint>

#define B_    8
#define CIN_  256
#define COUT_ 256
#define K_    4
#define H_    128
#define W_    128
#define HW_   (H_ * W_)    // 16384
#define P_    (B_ * HW_)   // 131072
#define BN_EPS 1e-5f

typedef __attribute__((ext_vector_type(8))) short bf16x8_t;   // 8 bf16 payloads (4 VGPRs)
typedef __attribute__((ext_vector_type(4))) float f32x4_t;

// fp32 -> bf16 payload, round-to-nearest-even
__device__ __forceinline__ unsigned short f2bf(float f) {
    unsigned int u = __float_as_uint(f);
    u += 0x7fffu + ((u >> 16) & 1u);
    return (unsigned short)(u >> 16);
}
// bf16 payload (low 16 bits of u) -> fp32
__device__ __forceinline__ float bf2f_lo(unsigned int u) { return __uint_as_float(u << 16); }
__device__ __forceinline__ float bf2f_hi(unsigned int u) { return __uint_as_float(u & 0xffff0000u); }

// async global->LDS, 16B per lane; lds base must be wave-uniform (HW adds lane*16)
#define GL2LDS(g, l)                                                                     \
    __builtin_amdgcn_global_load_lds((const __attribute__((address_space(1))) void*)(g), \
                                     (__attribute__((address_space(3))) void*)(l), 16, 0, 0)

// ---------------------------------------------------------------------------
// K0: cast conv_w / out_w (both [256][256], K-contiguous) to bf16.
// ---------------------------------------------------------------------------
__global__ __launch_bounds__(256) void k_wcast(
    const float* __restrict__ w0, const float* __restrict__ w1,
    unsigned short* __restrict__ o0, unsigned short* __restrict__ o1)
{
    const int i = (blockIdx.x * 256 + threadIdx.x) * 4;   // grid covers 65536 elems
    float4 a = *(const float4*)&w0[i];
    float4 b = *(const float4*)&w1[i];
    uint2 pa, pb;
    pa.x = (unsigned)f2bf(a.x) | ((unsigned)f2bf(a.y) << 16);
    pa.y = (unsigned)f2bf(a.z) | ((unsigned)f2bf(a.w) << 16);
    pb.x = (unsigned)f2bf(b.x) | ((unsigned)f2bf(b.y) << 16);
    pb.y = (unsigned)f2bf(b.z) | ((unsigned)f2bf(b.w) << 16);
    *(uint2*)&o0[i] = pa;
    *(uint2*)&o1[i] = pb;
}

// ---------------------------------------------------------------------------
// K1: flows + softmax weights + pixel-major bf16 transpose of x.
// Block = 256 px (one batch image slice); iterates c, staging a 256px x 64c
// bf16 tile in LDS per chunk, then writes xT[p][c] coalesced.
// ---------------------------------------------------------------------------
__global__ __launch_bounds__(256) void k_flows(
    const float* __restrict__ x, const float* __restrict__ off_w,
    const float* __restrict__ off_b, const float* __restrict__ wgt_w,
    const float* __restrict__ wgt_b, unsigned short* __restrict__ xT,
    float* __restrict__ coords, float* __restrict__ swts)
{
    __shared__ float coef[12 * 256];                     // [j][c]
    __shared__ alignas(16) unsigned short tile[256 * 68]; // [px][c_local], pitch 68
    const int t = threadIdx.x;
    for (int idx = t; idx < 12 * 256; idx += 256)
        coef[idx] = (idx < 8 * 256) ? off_w[idx] : wgt_w[idx - 8 * 256];
    __syncthreads();

    const int p  = blockIdx.x * 256 + t;
    const int b  = p >> 14;
    const int hw = p & (HW_ - 1);
    const float* xp = x + (size_t)b * (256 * HW_) + hw;
    const int px0 = blockIdx.x * 256;

    float acc[12];
#pragma unroll
    for (int j = 0; j < 12; ++j) acc[j] = 0.f;

    for (int chunk = 0; chunk < 4; ++chunk) {
        const int cbase = chunk * 64;
#pragma unroll 4
        for (int cc = 0; cc < 64; ++cc) {
            const float xv = xp[(size_t)(cbase + cc) * HW_];
            tile[t * 68 + cc] = f2bf(xv);
#pragma unroll
            for (int j = 0; j < 12; ++j)
                acc[j] = fmaf(xv, coef[j * 256 + cbase + cc], acc[j]);
        }
        __syncthreads();
        // flush transposed chunk: 256 px x 64 c, uint2 (4 bf16) per thread
#pragma unroll
        for (int pass = 0; pass < 16; ++pass) {
            const int px = pass * 16 + (t >> 4);
            const int j4 = (t & 15) * 4;
            const uint2 v = *(const uint2*)&tile[px * 68 + j4];
            *(uint2*)&xT[(size_t)(px0 + px) * 256 + cbase + j4] = v;
        }
        __syncthreads();
    }

    const int w = hw & (W_ - 1);
    const int h = hw >> 7;
    float l[4];
#pragma unroll
    for (int k = 0; k < 4; ++k) {
        const float fx = acc[k * 2 + 0] + off_b[k * 2 + 0];
        const float fy = acc[k * 2 + 1] + off_b[k * 2 + 1];
        coords[(size_t)p * 8 + k * 2 + 0] = (float)w + fx;  // unnorm(norm(.)) == identity
        coords[(size_t)p * 8 + k * 2 + 1] = (float)h + fy;
        l[k] = acc[8 + k] + wgt_b[k];
    }
    const float m  = fmaxf(fmaxf(l[0], l[1]), fmaxf(l[2], l[3]));
    const float e0 = __expf(l[0] - m), e1 = __expf(l[1] - m);
    const float e2 = __expf(l[2] - m), e3 = __expf(l[3] - m);
    const float inv = 1.f / (e0 + e1 + e2 + e3);
    swts[(size_t)p * 4 + 0] = e0 * inv;
    swts[(size_t)p * 4 + 1] = e1 * inv;
    swts[(size_t)p * 4 + 2] = e2 * inv;
    swts[(size_t)p * 4 + 3] = e3 * inv;
}

// ---------------------------------------------------------------------------
// GEMM core pieces (shared by k_proj / k_out):
// C[m=px][n=o] = sum_c A[px][c] * W[o][c], A/W bf16 K-contiguous.
// Block 256 thr = 4 waves; tile 128x128, BK=64; fragment-major LDS:
// frag-block (16 rows x 32 k = 1024B) stored in ds lane-order so
// global_load_lds(16B/lane) stages it and ds_read_b128 is conflict-free.
// Wave w computes 64x64 quadrant (mh=(w&1)*64, nh=(w>>1)*64).
// ---------------------------------------------------------------------------
#define GEMM_STAGE_AND_MFMA(A_, W_ptr_, smem_)                                              \
    char* As = smem_;                                                                       \
    char* Bs = smem_ + 16384;                                                               \
    const int w  = t >> 6;                                                                  \
    const int l  = t & 63;                                                                  \
    const int lr = l & 15;                                                                  \
    const int lq = l >> 4;                                                                  \
    f32x4_t acc[4][4];                                                                      \
    _Pragma("unroll") for (int i = 0; i < 4; ++i)                                           \
        _Pragma("unroll") for (int j = 0; j < 4; ++j)                                       \
            acc[i][j] = (f32x4_t){0.f, 0.f, 0.f, 0.f};                                      \
    const int wm = (w & 1) * 4;                                                             \
    const int wn = (w >> 1) * 4;                                                            \
    _Pragma("unroll") for (int ks = 0; ks < 4; ++ks) {                                      \
        const int k0 = ks * 64;                                                             \
        __syncthreads();                                                                    \
        _Pragma("unroll") for (int i = 0; i < 2; ++i) {                                     \
            const int mt = 2 * w + i;                                                       \
            _Pragma("unroll") for (int kc = 0; kc < 2; ++kc) {                              \
                const unsigned short* g =                                                   \
                    A_ + (size_t)(p0 + mt * 16 + lr) * 256 + k0 + kc * 32 + lq * 8;         \
                GL2LDS(g, As + (kc * 8 + mt) * 1024);                                       \
            }                                                                               \
        }                                                                                   \
        _Pragma("unroll") for (int i = 0; i < 2; ++i) {                                     \
            const int nt = 2 * w + i;                                                       \
            _Pragma("unroll") for (int kc = 0; kc < 2; ++kc) {                              \
                const unsigned short* g =                                                   \
                    W_ptr_ + (size_t)(n0 + nt * 16 + lr) * 256 + k0 + kc * 32 + lq * 8;     \
                GL2LDS(g, Bs + (kc * 8 + nt) * 1024);                                       \
            }                                                                               \
        }                                                                                   \
        __syncthreads();                                                                    \
        _Pragma("unroll") for (int kc = 0; kc < 2; ++kc) {                                  \
            bf16x8_t af[4], bfr[4];                                                         \
            _Pragma("unroll") for (int i = 0; i < 4; ++i)                                   \
                af[i] = *(const bf16x8_t*)(As + (kc * 8 + wm + i) * 1024 + l * 16);         \
            _Pragma("unroll") for (int j = 0; j < 4; ++j)                                   \
                bfr[j] = *(const bf16x8_t*)(Bs + (kc * 8 + wn + j) * 1024 + l * 16);        \
            _Pragma("unroll") for (int i = 0; i < 4; ++i)                                   \
                _Pragma("unroll") for (int j = 0; j < 4; ++j)                               \
                    acc[i][j] =                                                             \
                        __builtin_amdgcn_mfma_f32_16x16x32_bf16(af[i], bfr[j], acc[i][j],   \
                                                                0, 0, 0);                   \
        }                                                                                   \
    }

// K2: proj = xT . conv_w^T + conv_b -> bf16 pixel-major [p][o] (LDS-bounced stores)
__global__ __launch_bounds__(256, 2) void k_proj(
    const unsigned short* __restrict__ A, const unsigned short* __restrict__ Wb,
    const float* __restrict__ bias, unsigned short* __restrict__ Cout)
{
    __shared__ alignas(16) char smem[33792];   // staging 32KB; epilogue 128x132 ushort
    const int t  = threadIdx.x;
    const int bx = blockIdx.x;
    const int n0 = (bx & 1) * 128;
    const int p0 = (bx >> 1) * 128;

    GEMM_STAGE_AND_MFMA(A, Wb, smem)

    __syncthreads();   // all waves done with staging LDS before epilogue reuse
    unsigned short* ep = (unsigned short*)smem;
    const int mh = (w & 1) * 64, nh = (w >> 1) * 64;
#pragma unroll
    for (int j = 0; j < 4; ++j) {
        const int   col = nh + j * 16 + lr;
        const float bv  = bias[n0 + col];
#pragma unroll
        for (int i = 0; i < 4; ++i) {
#pragma unroll
            for (int r = 0; r < 4; ++r) {
                const int row = mh + i * 16 + lq * 4 + r;
                ep[row * 132 + col] = f2bf(acc[i][j][r] + bv);
            }
        }
    }
    __syncthreads();
#pragma unroll
    for (int pass = 0; pass < 16; ++pass) {
        const int row = pass * 8 + (t >> 5);
        const int c4  = (t & 31) * 4;
        const uint2 v = *(const uint2*)&ep[row * 132 + c4];
        *(uint2*)&Cout[(size_t)(p0 + row) * 256 + n0 + c4] = v;
    }
}

// K4: out = featbn . out_w^T + out_b -> fp32 channel-major [b][n][hw].
// Lane's 4 acc regs are 4 consecutive px at fixed n -> direct float4 stores.
__global__ __launch_bounds__(256, 2) void k_out(
    const unsigned short* __restrict__ A, const unsigned short* __restrict__ Wb,
    const float* __restrict__ bias, float* __restrict__ Cout)
{
    __shared__ alignas(16) char smem[32768];
    const int t  = threadIdx.x;
    const int bx = blockIdx.x;
    const int n0 = (bx & 1) * 128;
    const int p0 = (bx >> 1) * 128;

    GEMM_STAGE_AND_MFMA(A, Wb, smem)

    const int mh = (w & 1) * 64, nh = (w >> 1) * 64;
    const int b   = p0 >> 14;
    const int hw0 = p0 & (HW_ - 1);
#pragma unroll
    for (int j = 0; j < 4; ++j) {
        const int   n  = n0 + nh + j * 16 + lr;
        const float bb = bias[n];
#pragma unroll
        for (int i = 0; i < 4; ++i) {
            f32x4_t v = acc[i][j];
            v[0] += bb; v[1] += bb; v[2] += bb; v[3] += bb;
            *(f32x4_t*)&Cout[(size_t)(b * 256 + n) * HW_ + hw0 + mh + i * 16 + lq * 4] = v;
        }
    }
}

// ---------------------------------------------------------------------------
// K3: bilinear sample + weighted sum + residual + BN (eval), bf16 in/out.
// 2 channels per lane (bf16x2 = 4B loads); 128 lanes cover a 512B row read.
// Block handles 8 pixels (2 at a time across thread halves).
// ---------------------------------------------------------------------------
__global__ __launch_bounds__(256) void k_sample(
    const unsigned short* __restrict__ proj, const float* __restrict__ coords,
    const float* __restrict__ swts,
    const float* __restrict__ gamma, const float* __restrict__ beta,
    const float* __restrict__ rmean, const float* __restrict__ rvar,
    unsigned short* __restrict__ feat)
{
    const int t  = threadIdx.x;
    const int t7 = t & 127;
    const int ph = t >> 7;
    const int c  = t7 * 2;
    const float2 mn = *(const float2*)&rmean[c];
    const float2 vr = *(const float2*)&rvar[c];
    const float2 gm = *(const float2*)&gamma[c];
    const float2 bt = *(const float2*)&beta[c];
    const float inv0 = gm.x * rsqrtf(vr.x + BN_EPS);
    const float inv1 = gm.y * rsqrtf(vr.y + BN_EPS);

    const int pbase = blockIdx.x * 8;
    const int b = pbase >> 14;
    const unsigned short* projb = proj + (size_t)b * HW_ * 256;

#pragma unroll
    for (int it = 0; it < 4; ++it) {
        const int p = pbase + it * 2 + ph;
        const unsigned int sv = *(const unsigned int*)&proj[(size_t)p * 256 + c];
        float a0 = bf2f_lo(sv & 0xffffu);
        float a1 = bf2f_hi(sv);
#pragma unroll
        for (int k = 0; k < 4; ++k) {
            const float sx = coords[(size_t)p * 8 + k * 2 + 0];
            const float sy = coords[(size_t)p * 8 + k * 2 + 1];
            const float wk = swts[(size_t)p * 4 + k];
            const float x0f = floorf(sx), y0f = floorf(sy);
            const float fx = sx - x0f, fy = sy - y0f;
            const float vx0 = (x0f >= 0.f && x0f <= (float)(W_ - 1)) ? 1.f : 0.f;
            const float vx1 = (x0f >= -1.f && x0f <= (float)(W_ - 2)) ? 1.f : 0.f;
            const float vy0 = (y0f >= 0.f && y0f <= (float)(H_ - 1)) ? 1.f : 0.f;
            const float vy1 = (y0f >= -1.f && y0f <= (float)(H_ - 2)) ? 1.f : 0.f;
            const int x0 = (int)x0f, y0 = (int)y0f;
            const int cx0 = min(max(x0, 0), W_ - 1);
            const int cx1 = min(max(x0 + 1, 0), W_ - 1);
            const int cy0 = min(max(y0, 0), H_ - 1);
            const int cy1 = min(max(y0 + 1, 0), H_ - 1);
            const float w00 = (1.f - fx) * (1.f - fy) * wk * vx0 * vy0;
            const float w10 = fx * (1.f - fy) * wk * vx1 * vy0;
            const float w01 = (1.f - fx) * fy * wk * vx0 * vy1;
            const float w11 = fx * fy * wk * vx1 * vy1;
            const unsigned int v00 = *(const unsigned int*)&projb[(size_t)(cy0 * W_ + cx0) * 256 + c];
            const unsigned int v10 = *(const unsigned int*)&projb[(size_t)(cy0 * W_ + cx1) * 256 + c];
            const unsigned int v01 = *(const unsigned int*)&projb[(size_t)(cy1 * W_ + cx0) * 256 + c];
            const unsigned int v11 = *(const unsigned int*)&projb[(size_t)(cy1 * W_ + cx1) * 256 + c];
            a0 = fmaf(w00, bf2f_lo(v00 & 0xffffu), a0);
            a1 = fmaf(w00, bf2f_hi(v00), a1);
            a0 = fmaf(w10, bf2f_lo(v10 & 0xffffu), a0);
            a1 = fmaf(w10, bf2f_hi(v10), a1);
            a0 = fmaf(w01, bf2f_lo(v01 & 0xffffu), a0);
            a1 = fmaf(w01, bf2f_hi(v01), a1);
            a0 = fmaf(w11, bf2f_lo(v11 & 0xffffu), a0);
            a1 = fmaf(w11, bf2f_hi(v11), a1);
        }
        const float r0 = (a0 - mn.x) * inv0 + bt.x;
        const float r1 = (a1 - mn.y) * inv1 + bt.y;
        const unsigned int o = (unsigned)f2bf(r0) | ((unsigned)f2bf(r1) << 16);
        *(unsigned int*)&feat[(size_t)p * 256 + c] = o;
    }
}

extern "C" void kernel_launch(void* const* d_in, const int* in_sizes, int n_in,
                              void* d_out, int out_size, void* d_ws, size_t ws_size,
                              hipStream_t stream)
{
    const float* x      = (const float*)d_in[0];
    const float* conv_w = (const float*)d_in[1];
    const float* conv_b = (const float*)d_in[2];
    const float* off_w  = (const float*)d_in[3];
    const float* off_b  = (const float*)d_in[4];
    const float* wgt_w  = (const float*)d_in[5];
    const float* wgt_b  = (const float*)d_in[6];
    const float* gamma  = (const float*)d_in[7];
    const float* beta   = (const float*)d_in[8];
    const float* rmean  = (const float*)d_in[9];
    const float* rvar   = (const float*)d_in[10];
    const float* out_w  = (const float*)d_in[11];
    const float* out_b  = (const float*)d_in[12];

    char* ws = (char*)d_ws;
    unsigned short* xT     = (unsigned short*)(ws);                         // 64 MiB
    unsigned short* proj   = (unsigned short*)(ws + (size_t)67108864);      // 64 MiB
    unsigned short* feat   = (unsigned short*)(ws + (size_t)134217728);     // 64 MiB
    float*          coords = (float*)(ws + (size_t)201326592);              // 4 MiB
    float*          swts   = (float*)(ws + (size_t)205520896);              // 2 MiB
    unsigned short* wA     = (unsigned short*)(ws + (size_t)207618048);     // 128 KiB
    unsigned short* wB     = (unsigned short*)(ws + (size_t)207749120);     // 128 KiB

    k_wcast <<<64,          256, 0, stream>>>(conv_w, out_w, wA, wB);
    k_flows <<<P_ / 256,    256, 0, stream>>>(x, off_w, off_b, wgt_w, wgt_b, xT, coords, swts);
    k_proj  <<<(P_/128)*2,  256, 0, stream>>>(xT, wA, conv_b, proj);
    k_sample<<<P_ / 8,      256, 0, stream>>>(proj, coords, swts, gamma, beta, rmean, rvar, feat);
    k_out   <<<(P_/128)*2,  256, 0, stream>>>(feat, wB, out_b, (float*)d_out);
}

// Round 3
// 426.330 us; speedup vs baseline: 1.9142x; 1.0709x over previous
//
#include <hip/hip_runtime.h>
#include <cstddef>
#include <cstdint>

#define B_    8
#define CIN_  256
#define COUT_ 256
#define K_    4
#define H_    128
#define W_    128
#define HW_   (H_ * W_)    // 16384
#define P_    (B_ * HW_)   // 131072
#define BN_EPS 1e-5f

typedef __attribute__((ext_vector_type(8))) short bf16x8_t;   // 8 bf16 payloads (4 VGPRs)
typedef __attribute__((ext_vector_type(4))) float f32x4_t;

// fp32 -> bf16 payload, round-to-nearest-even
__device__ __forceinline__ unsigned short f2bf(float f) {
    unsigned int u = __float_as_uint(f);
    u += 0x7fffu + ((u >> 16) & 1u);
    return (unsigned short)(u >> 16);
}
// uint holding 2 bf16 -> float2 (2 VALU ops)
__device__ __forceinline__ float2 up2(unsigned int u) {
    return make_float2(__uint_as_float(u << 16), __uint_as_float(u & 0xffff0000u));
}
__device__ __forceinline__ void fma2(float2& d, float s, float2 v) {
    d.x = fmaf(s, v.x, d.x);
    d.y = fmaf(s, v.y, d.y);
}

// async global->LDS, 16B per lane; lds base must be wave-uniform (HW adds lane*16)
#define GL2LDS(g, l)                                                                     \
    __builtin_amdgcn_global_load_lds((const __attribute__((address_space(1))) void*)(g), \
                                     (__attribute__((address_space(3))) void*)(l), 16, 0, 0)

// ---------------------------------------------------------------------------
// K0: prep. Blocks 0..63: cast conv_w to bf16. Block 64: fold BN into out_w:
//   wB'[n][c] = bf16(out_w[n][c] * inv[c]),  inv = gamma/sqrt(var+eps)
//   bias'[n]  = out_b[n] + sum_c (beta[c] - mean[c]*inv[c]) * out_w[n][c]
// ---------------------------------------------------------------------------
__global__ __launch_bounds__(256) void k_prep(
    const float* __restrict__ conv_w, const float* __restrict__ out_w,
    const float* __restrict__ gamma, const float* __restrict__ beta,
    const float* __restrict__ rmean, const float* __restrict__ rvar,
    const float* __restrict__ out_b,
    unsigned short* __restrict__ wA, unsigned short* __restrict__ wB,
    float* __restrict__ bias2)
{
    const int t = threadIdx.x;
    if (blockIdx.x < 64) {
        const int i = (blockIdx.x * 256 + t) * 4;
        float4 a = *(const float4*)&conv_w[i];
        uint2 pa;
        pa.x = (unsigned)f2bf(a.x) | ((unsigned)f2bf(a.y) << 16);
        pa.y = (unsigned)f2bf(a.z) | ((unsigned)f2bf(a.w) << 16);
        *(uint2*)&wA[i] = pa;
    } else {
        __shared__ float sinv[256], sd[256];
        const float iv = gamma[t] * rsqrtf(rvar[t] + BN_EPS);
        sinv[t] = iv;
        sd[t]   = beta[t] - rmean[t] * iv;
        __syncthreads();
        float acc = out_b[t];
        for (int c = 0; c < 256; c += 4) {
            const float4 wv = *(const float4*)&out_w[t * 256 + c];
            acc += sd[c] * wv.x + sd[c + 1] * wv.y + sd[c + 2] * wv.z + sd[c + 3] * wv.w;
            uint2 p;
            p.x = (unsigned)f2bf(wv.x * sinv[c])     | ((unsigned)f2bf(wv.y * sinv[c + 1]) << 16);
            p.y = (unsigned)f2bf(wv.z * sinv[c + 2]) | ((unsigned)f2bf(wv.w * sinv[c + 3]) << 16);
            *(uint2*)&wB[t * 256 + c] = p;
        }
        bias2[t] = acc;
    }
}

// ---------------------------------------------------------------------------
// K1: flows + softmax + bilinear coefficient table + pixel-major bf16 x^T.
// Per (p,k) emits float4 corner weights (softmax & validity folded) and
// int4 clamped corner element-offsets (units of ushort, within image b).
// SoA [k][p] so stores coalesce.
// ---------------------------------------------------------------------------
__global__ __launch_bounds__(256) void k_flows(
    const float* __restrict__ x, const float* __restrict__ off_w,
    const float* __restrict__ off_b, const float* __restrict__ wgt_w,
    const float* __restrict__ wgt_b, unsigned short* __restrict__ xT,
    float4* __restrict__ tabW, int4* __restrict__ tabI)
{
    __shared__ float coef[12 * 256];                      // [j][c]
    __shared__ alignas(16) unsigned short tile[256 * 68]; // [px][c_local], pitch 68
    const int t = threadIdx.x;
    for (int idx = t; idx < 12 * 256; idx += 256)
        coef[idx] = (idx < 8 * 256) ? off_w[idx] : wgt_w[idx - 8 * 256];
    __syncthreads();

    const int p  = blockIdx.x * 256 + t;
    const int b  = p >> 14;
    const int hw = p & (HW_ - 1);
    const float* xp = x + (size_t)b * (256 * HW_) + hw;
    const int px0 = blockIdx.x * 256;

    float acc[12];
#pragma unroll
    for (int j = 0; j < 12; ++j) acc[j] = 0.f;

    for (int chunk = 0; chunk < 4; ++chunk) {
        const int cbase = chunk * 64;
#pragma unroll 4
        for (int cc = 0; cc < 64; ++cc) {
            const float xv = xp[(size_t)(cbase + cc) * HW_];
            tile[t * 68 + cc] = f2bf(xv);
#pragma unroll
            for (int j = 0; j < 12; ++j)
                acc[j] = fmaf(xv, coef[j * 256 + cbase + cc], acc[j]);
        }
        __syncthreads();
#pragma unroll
        for (int pass = 0; pass < 16; ++pass) {
            const int px = pass * 16 + (t >> 4);
            const int j4 = (t & 15) * 4;
            const uint2 v = *(const uint2*)&tile[px * 68 + j4];
            *(uint2*)&xT[(size_t)(px0 + px) * 256 + cbase + j4] = v;
        }
        __syncthreads();
    }

    const int w = hw & (W_ - 1);
    const int h = hw >> 7;
    float l[4];
#pragma unroll
    for (int k = 0; k < 4; ++k) l[k] = acc[8 + k] + wgt_b[k];
    const float m  = fmaxf(fmaxf(l[0], l[1]), fmaxf(l[2], l[3]));
    const float e0 = __expf(l[0] - m), e1 = __expf(l[1] - m);
    const float e2 = __expf(l[2] - m), e3 = __expf(l[3] - m);
    const float sinv = 1.f / (e0 + e1 + e2 + e3);
    float wk[4] = {e0 * sinv, e1 * sinv, e2 * sinv, e3 * sinv};

#pragma unroll
    for (int k = 0; k < 4; ++k) {
        const float sx = (float)w + acc[k * 2 + 0] + off_b[k * 2 + 0];  // unnorm(norm(.)) == id
        const float sy = (float)h + acc[k * 2 + 1] + off_b[k * 2 + 1];
        const float x0f = floorf(sx), y0f = floorf(sy);
        const float fx = sx - x0f, fy = sy - y0f;
        const float vx0 = (x0f >= 0.f  && x0f <= (float)(W_ - 1)) ? 1.f : 0.f;
        const float vx1 = (x0f >= -1.f && x0f <= (float)(W_ - 2)) ? 1.f : 0.f;
        const float vy0 = (y0f >= 0.f  && y0f <= (float)(H_ - 1)) ? 1.f : 0.f;
        const float vy1 = (y0f >= -1.f && y0f <= (float)(H_ - 2)) ? 1.f : 0.f;
        const int x0 = (int)x0f, y0 = (int)y0f;
        const int cx0 = min(max(x0, 0), W_ - 1);
        const int cx1 = min(max(x0 + 1, 0), W_ - 1);
        const int cy0 = min(max(y0, 0), H_ - 1);
        const int cy1 = min(max(y0 + 1, 0), H_ - 1);
        float4 wv;
        wv.x = (1.f - fx) * (1.f - fy) * wk[k] * vx0 * vy0;
        wv.y = fx * (1.f - fy) * wk[k] * vx1 * vy0;
        wv.z = (1.f - fx) * fy * wk[k] * vx0 * vy1;
        wv.w = fx * fy * wk[k] * vx1 * vy1;
        int4 ov;
        ov.x = (cy0 * W_ + cx0) * 256;
        ov.y = (cy0 * W_ + cx1) * 256;
        ov.z = (cy1 * W_ + cx0) * 256;
        ov.w = (cy1 * W_ + cx1) * 256;
        tabW[(size_t)k * P_ + p] = wv;
        tabI[(size_t)k * P_ + p] = ov;
    }
}

// ---------------------------------------------------------------------------
// GEMM core (shared by k_proj / k_out): C[m=px][n=o] = sum_c A[px][c]*W[o][c]
// 128x128 tile, BK=64, fragment-major LDS staged via global_load_lds(16B).
// ---------------------------------------------------------------------------
#define GEMM_STAGE_AND_MFMA(A_, W_ptr_, smem_)                                              \
    char* As = smem_;                                                                       \
    char* Bs = smem_ + 16384;                                                               \
    const int w  = t >> 6;                                                                  \
    const int l  = t & 63;                                                                  \
    const int lr = l & 15;                                                                  \
    const int lq = l >> 4;                                                                  \
    f32x4_t acc[4][4];                                                                      \
    _Pragma("unroll") for (int i = 0; i < 4; ++i)                                           \
        _Pragma("unroll") for (int j = 0; j < 4; ++j)                                       \
            acc[i][j] = (f32x4_t){0.f, 0.f, 0.f, 0.f};                                      \
    const int wm = (w & 1) * 4;                                                             \
    const int wn = (w >> 1) * 4;                                                            \
    _Pragma("unroll") for (int ks = 0; ks < 4; ++ks) {                                      \
        const int k0 = ks * 64;                                                             \
        __syncthreads();                                                                    \
        _Pragma("unroll") for (int i = 0; i < 2; ++i) {                                     \
            const int mt = 2 * w + i;                                                       \
            _Pragma("unroll") for (int kc = 0; kc < 2; ++kc) {                              \
                const unsigned short* g =                                                   \
                    A_ + (size_t)(p0 + mt * 16 + lr) * 256 + k0 + kc * 32 + lq * 8;         \
                GL2LDS(g, As + (kc * 8 + mt) * 1024);                                       \
            }                                                                               \
        }                                                                                   \
        _Pragma("unroll") for (int i = 0; i < 2; ++i) {                                     \
            const int nt = 2 * w + i;                                                       \
            _Pragma("unroll") for (int kc = 0; kc < 2; ++kc) {                              \
                const unsigned short* g =                                                   \
                    W_ptr_ + (size_t)(n0 + nt * 16 + lr) * 256 + k0 + kc * 32 + lq * 8;     \
                GL2LDS(g, Bs + (kc * 8 + nt) * 1024);                                       \
            }                                                                               \
        }                                                                                   \
        __syncthreads();                                                                    \
        _Pragma("unroll") for (int kc = 0; kc < 2; ++kc) {                                  \
            bf16x8_t af[4], bfr[4];                                                         \
            _Pragma("unroll") for (int i = 0; i < 4; ++i)                                   \
                af[i] = *(const bf16x8_t*)(As + (kc * 8 + wm + i) * 1024 + l * 16);         \
            _Pragma("unroll") for (int j = 0; j < 4; ++j)                                   \
                bfr[j] = *(const bf16x8_t*)(Bs + (kc * 8 + wn + j) * 1024 + l * 16);        \
            _Pragma("unroll") for (int i = 0; i < 4; ++i)                                   \
                _Pragma("unroll") for (int j = 0; j < 4; ++j)                               \
                    acc[i][j] =                                                             \
                        __builtin_amdgcn_mfma_f32_16x16x32_bf16(af[i], bfr[j], acc[i][j],   \
                                                                0, 0, 0);                   \
        }                                                                                   \
    }

// K2: proj = xT . conv_w^T + conv_b -> bf16 pixel-major [p][o]
__global__ __launch_bounds__(256, 3) void k_proj(
    const unsigned short* __restrict__ A, const unsigned short* __restrict__ Wb,
    const float* __restrict__ bias, unsigned short* __restrict__ Cout)
{
    __shared__ alignas(16) char smem[33792];
    const int t  = threadIdx.x;
    const int bx = blockIdx.x;
    const int n0 = (bx & 1) * 128;
    const int p0 = (bx >> 1) * 128;

    GEMM_STAGE_AND_MFMA(A, Wb, smem)

    __syncthreads();
    unsigned short* ep = (unsigned short*)smem;
    const int mh = (w & 1) * 64, nh = (w >> 1) * 64;
#pragma unroll
    for (int j = 0; j < 4; ++j) {
        const int   col = nh + j * 16 + lr;
        const float bv  = bias[n0 + col];
#pragma unroll
        for (int i = 0; i < 4; ++i) {
#pragma unroll
            for (int r = 0; r < 4; ++r) {
                const int row = mh + i * 16 + lq * 4 + r;
                ep[row * 132 + col] = f2bf(acc[i][j][r] + bv);
            }
        }
    }
    __syncthreads();
#pragma unroll
    for (int pass = 0; pass < 16; ++pass) {
        const int row = pass * 8 + (t >> 5);
        const int c4  = (t & 31) * 4;
        const uint2 v = *(const uint2*)&ep[row * 132 + c4];
        *(uint2*)&Cout[(size_t)(p0 + row) * 256 + n0 + c4] = v;
    }
}

// K4: out = feat . wB'^T + bias' -> fp32 channel-major [b][n][hw]
__global__ __launch_bounds__(256, 3) void k_out(
    const unsigned short* __restrict__ A, const unsigned short* __restrict__ Wb,
    const float* __restrict__ bias, float* __restrict__ Cout)
{
    __shared__ alignas(16) char smem[32768];
    const int t  = threadIdx.x;
    const int bx = blockIdx.x;
    const int n0 = (bx & 1) * 128;
    const int p0 = (bx >> 1) * 128;

    GEMM_STAGE_AND_MFMA(A, Wb, smem)

    const int mh = (w & 1) * 64, nh = (w >> 1) * 64;
    const int b   = p0 >> 14;
    const int hw0 = p0 & (HW_ - 1);
#pragma unroll
    for (int j = 0; j < 4; ++j) {
        const int   n  = n0 + nh + j * 16 + lr;
        const float bb = bias[n];
#pragma unroll
        for (int i = 0; i < 4; ++i) {
            f32x4_t v = acc[i][j];
            v[0] += bb; v[1] += bb; v[2] += bb; v[3] += bb;
            *(f32x4_t*)&Cout[(size_t)(b * 256 + n) * HW_ + hw0 + mh + i * 16 + lq * 4] = v;
        }
    }
}

// ---------------------------------------------------------------------------
// K3: gather + weighted sum + residual (BN folded into k_out weights).
// 8 channels/lane (uint4 = 16B gathers), 32 lanes per pixel, no coord math.
// ---------------------------------------------------------------------------
__global__ __launch_bounds__(256) void k_sample(
    const unsigned short* __restrict__ proj, const float4* __restrict__ tabW,
    const int4* __restrict__ tabI, unsigned short* __restrict__ feat)
{
    const int t  = threadIdx.x;
    const int w  = t >> 6;
    const int l  = t & 63;
    const int ph = l >> 5;
    const int c0 = (l & 31) * 8;

    const int pbase = blockIdx.x * 16;     // 16384 % 16 == 0: same b for whole block
    const int b = pbase >> 14;
    const unsigned short* projb = proj + (size_t)b * HW_ * 256;

#pragma unroll
    for (int it = 0; it < 2; ++it) {
        const int p = pbase + it * 8 + w * 2 + ph;
        const uint4 rv = *(const uint4*)&proj[(size_t)p * 256 + c0];
        float2 a0 = up2(rv.x), a1 = up2(rv.y), a2 = up2(rv.z), a3 = up2(rv.w);
#pragma unroll
        for (int k = 0; k < 4; ++k) {
            const float4 wv = tabW[(size_t)k * P_ + p];   // broadcast within half-wave
            const int4   ov = tabI[(size_t)k * P_ + p];
            const uint4 g0 = *(const uint4*)&projb[ov.x + c0];
            const uint4 g1 = *(const uint4*)&projb[ov.y + c0];
            const uint4 g2 = *(const uint4*)&projb[ov.z + c0];
            const uint4 g3 = *(const uint4*)&projb[ov.w + c0];
            fma2(a0, wv.x, up2(g0.x)); fma2(a1, wv.x, up2(g0.y));
            fma2(a2, wv.x, up2(g0.z)); fma2(a3, wv.x, up2(g0.w));
            fma2(a0, wv.y, up2(g1.x)); fma2(a1, wv.y, up2(g1.y));
            fma2(a2, wv.y, up2(g1.z)); fma2(a3, wv.y, up2(g1.w));
            fma2(a0, wv.z, up2(g2.x)); fma2(a1, wv.z, up2(g2.y));
            fma2(a2, wv.z, up2(g2.z)); fma2(a3, wv.z, up2(g2.w));
            fma2(a0, wv.w, up2(g3.x)); fma2(a1, wv.w, up2(g3.y));
            fma2(a2, wv.w, up2(g3.z)); fma2(a3, wv.w, up2(g3.w));
        }
        uint4 o;
        o.x = (unsigned)f2bf(a0.x) | ((unsigned)f2bf(a0.y) << 16);
        o.y = (unsigned)f2bf(a1.x) | ((unsigned)f2bf(a1.y) << 16);
        o.z = (unsigned)f2bf(a2.x) | ((unsigned)f2bf(a2.y) << 16);
        o.w = (unsigned)f2bf(a3.x) | ((unsigned)f2bf(a3.y) << 16);
        *(uint4*)&feat[(size_t)p * 256 + c0] = o;
    }
}

extern "C" void kernel_launch(void* const* d_in, const int* in_sizes, int n_in,
                              void* d_out, int out_size, void* d_ws, size_t ws_size,
                              hipStream_t stream)
{
    const float* x      = (const float*)d_in[0];
    const float* conv_w = (const float*)d_in[1];
    const float* conv_b = (const float*)d_in[2];
    const float* off_w  = (const float*)d_in[3];
    const float* off_b  = (const float*)d_in[4];
    const float* wgt_w  = (const float*)d_in[5];
    const float* wgt_b  = (const float*)d_in[6];
    const float* gamma  = (const float*)d_in[7];
    const float* beta   = (const float*)d_in[8];
    const float* rmean  = (const float*)d_in[9];
    const float* rvar   = (const float*)d_in[10];
    const float* out_w  = (const float*)d_in[11];
    const float* out_b  = (const float*)d_in[12];

    char* ws = (char*)d_ws;
    unsigned short* xT   = (unsigned short*)(ws);                      // 64 MiB
    unsigned short* proj = (unsigned short*)(ws + (size_t)67108864);   // 64 MiB
    unsigned short* feat = (unsigned short*)(ws + (size_t)134217728);  // 64 MiB
    float4*         tabW = (float4*)(ws + (size_t)201326592);          // 8 MiB
    int4*           tabI = (int4*)(ws + (size_t)209715200);            // 8 MiB
    unsigned short* wA   = (unsigned short*)(ws + (size_t)218103808);  // 128 KiB
    unsigned short* wB   = (unsigned short*)(ws + (size_t)218234880);  // 128 KiB
    float*          bias2= (float*)(ws + (size_t)218365952);           // 1 KiB

    k_prep  <<<65,         256, 0, stream>>>(conv_w, out_w, gamma, beta, rmean, rvar,
                                             out_b, wA, wB, bias2);
    k_flows <<<P_ / 256,   256, 0, stream>>>(x, off_w, off_b, wgt_w, wgt_b, xT, tabW, tabI);
    k_proj  <<<(P_/128)*2, 256, 0, stream>>>(xT, wA, conv_b, proj);
    k_sample<<<P_ / 16,    256, 0, stream>>>(proj, tabW, tabI, feat);
    k_out   <<<(P_/128)*2, 256, 0, stream>>>(feat, wB, bias2, (float*)d_out);
}